// Round 1
// baseline (419.276 us; speedup 1.0000x reference)
//
#include <hip/hip_runtime.h>

#define S_LEN 1024
#define DH 64
#define QT 64
#define NCH 16
#define BLOCK 512
#define OUT_ELEMS (4*16*1024*64)

typedef _Float16 f16x8 __attribute__((ext_vector_type(8)));
typedef _Float16 f16x4 __attribute__((ext_vector_type(4)));
typedef float    f32x4 __attribute__((ext_vector_type(4)));

__global__ __launch_bounds__(BLOCK)
void attn_fused(const float* __restrict__ q, const float* __restrict__ k,
                const float* __restrict__ v, float* __restrict__ dout)
{
    // XCD-aware bijective swizzle: 1024 blocks = 8 XCDs x 128
    const int bid = blockIdx.x;
    const int nb  = (bid & 7) * 128 + (bid >> 3);
    const int bh  = nb >> 4;          // head index 0..63
    const int qt  = nb & 15;          // q-tile 0..15
    const int qbase = qt * QT;

    const float* __restrict__ qh = q + (size_t)bh * S_LEN * DH;
    const float* __restrict__ kh = k + (size_t)bh * S_LEN * DH;
    const float* __restrict__ vh = v + (size_t)bh * S_LEN * DH;
    float* __restrict__ outh  = dout + (size_t)bh * S_LEN * DH;
    float* __restrict__ attnh = dout + (size_t)OUT_ELEMS + (size_t)bh * S_LEN * S_LEN;

    // e_tile: unnormalized exp scores, fp16, XOR-swizzled rows (2048B row would be
    // 32-way bank conflict on ds_read_b128 otherwise — guide G4).
    __shared__ _Float16 e_tile[QT * S_LEN];            // 128 KB
    __shared__ _Float16 kvbuf[2][64 * 72];             // 18 KB: K chunks (row*64) / V^T chunks (d*72+row)
    __shared__ float    inv_l[QT];

    const int tid = threadIdx.x;
    const int w   = tid >> 6;     // wave 0..7
    const int l   = tid & 63;
    const int mg  = w & 3;        // M row-group (16 rows each)
    const int ng  = w >> 2;       // N col-group (0..1)
    const int ln  = l & 15;       // MFMA: A-row / B-col / C-col
    const int lg  = l >> 4;       // MFMA: k-subgroup / C row-quad

    const int st_row = tid >> 3;        // staging: row 0..63
    const int st_d0  = (tid & 7) * 8;   // staging: 8-float column chunk

    // ---- Q fragments (global -> reg, fp32 -> fp16). rows mg*16+ln, k-step s: d = s*32+lg*8+j
    f16x8 qf[2];
    {
        const float* qrow = qh + (size_t)(qbase + mg*16 + ln) * DH;
        #pragma unroll
        for (int s = 0; s < 2; ++s) {
            f32x4 a = *(const f32x4*)(qrow + s*32 + lg*8);
            f32x4 b = *(const f32x4*)(qrow + s*32 + lg*8 + 4);
            f16x8 f;
            #pragma unroll
            for (int j = 0; j < 4; ++j) { f[j] = (_Float16)a[j]; f[j+4] = (_Float16)b[j]; }
            qf[s] = f;
        }
    }

    f32x4 sa, sb;   // staging registers (issue-early, write-late)

    // ================= Phase A: QK^T -> exp -> e_tile =================
    {
        const float* p = kh + (size_t)st_row * DH + st_d0;
        sa = *(const f32x4*)p; sb = *(const f32x4*)(p + 4);
    }
    {
        f16x8 f;
        #pragma unroll
        for (int j = 0; j < 4; ++j) { f[j] = (_Float16)sa[j]; f[j+4] = (_Float16)sb[j]; }
        *(f16x8*)&kvbuf[0][st_row*64 + (st_d0 ^ ((st_row & 7) << 3))] = f;
    }
    __syncthreads();

    const float cexp = 0.18033688011112042f;   // log2(e)/8  (softmax scale fused into exp2)

    for (int c = 0; c < NCH; ++c) {
        const int cur = c & 1;
        if (c + 1 < NCH) {   // issue next K chunk loads early — latency hides under MFMA
            const float* p = kh + (size_t)((c+1)*64 + st_row) * DH + st_d0;
            sa = *(const f32x4*)p; sb = *(const f32x4*)(p + 4);
        }
        #pragma unroll
        for (int tj = 0; tj < 2; ++tj) {
            const int n0 = ng*32 + tj*16;
            const int brow = n0 + ln;
            f32x4 acc = {0.f, 0.f, 0.f, 0.f};
            #pragma unroll
            for (int s = 0; s < 2; ++s) {
                f16x8 bf = *(const f16x8*)&kvbuf[cur][brow*64 + ((s*32 + lg*8) ^ ((brow & 7) << 3))];
                acc = __builtin_amdgcn_mfma_f32_16x16x32_f16(qf[s], bf, acc, 0, 0, 0);
            }
            // e = exp(score/8): logits in [-8,8] -> no max-subtraction needed in fp32
            const int col = c*64 + n0 + ln;
            #pragma unroll
            for (int r = 0; r < 4; ++r) {
                const int row = mg*16 + lg*4 + r;
                float e = __builtin_amdgcn_exp2f(acc[r] * cexp);
                e_tile[row*S_LEN + (col ^ ((row & 7) << 3))] = (_Float16)e;
            }
        }
        if (c + 1 < NCH) {
            f16x8 f;
            #pragma unroll
            for (int j = 0; j < 4; ++j) { f[j] = (_Float16)sa[j]; f[j+4] = (_Float16)sb[j]; }
            *(f16x8*)&kvbuf[(c+1)&1][st_row*64 + (st_d0 ^ ((st_row & 7) << 3))] = f;
        }
        __syncthreads();
    }

    // ================= Phase B: row sums -> inv_l =================
    {
        const int row = tid >> 3;
        const int p0  = (tid & 7) * 128;
        float ssum = 0.f;
        #pragma unroll
        for (int i = 0; i < 16; ++i) {
            f16x8 ev = *(const f16x8*)&e_tile[row*S_LEN + ((p0 + i*8) ^ ((row & 7) << 3))];
            #pragma unroll
            for (int j = 0; j < 8; ++j) ssum += (float)ev[j];
        }
        ssum += __shfl_xor(ssum, 1);
        ssum += __shfl_xor(ssum, 2);
        ssum += __shfl_xor(ssum, 4);
        if ((tid & 7) == 0) inv_l[row] = 1.f / ssum;
    }
    __syncthreads();

    // ================= Phase C: PV MFMA + interleaved attn stores =================
    const float inv_a0 = inv_l[w*8 + lg];
    const float inv_a1 = inv_l[w*8 + 4 + lg];

    {
        const float* p = vh + (size_t)st_row * DH + st_d0;
        sa = *(const f32x4*)p; sb = *(const f32x4*)(p + 4);
    }
    {
        #pragma unroll
        for (int j = 0; j < 8; ++j) {   // transpose into V^T[d][vrow], stride 72 keeps b128 16B-aligned
            float x = (j < 4) ? sa[j] : sb[j-4];
            kvbuf[0][(st_d0 + j)*72 + st_row] = (_Float16)x;
        }
    }
    __syncthreads();

    f32x4 oacc0 = {0.f,0.f,0.f,0.f}, oacc1 = {0.f,0.f,0.f,0.f};

    for (int c = 0; c < NCH; ++c) {
        const int cur = c & 1;
        if (c + 1 < NCH) {
            const float* p = vh + (size_t)((c+1)*64 + st_row) * DH + st_d0;
            sa = *(const f32x4*)p; sb = *(const f32x4*)(p + 4);
        }
        // attn stores for column chunk c (fire-and-forget; drain under MFMAs)
        #pragma unroll
        for (int ps = 0; ps < 2; ++ps) {
            const int arow = w*8 + ps*4 + lg;
            const int acol = ln*4;
            f16x4 ev = *(const f16x4*)&e_tile[arow*S_LEN + ((c*64 + acol) ^ ((arow & 7) << 3))];
            const float inv = ps ? inv_a1 : inv_a0;
            f32x4 pv;
            #pragma unroll
            for (int j = 0; j < 4; ++j) pv[j] = (float)ev[j] * inv;
            *(f32x4*)&attnh[(size_t)(qbase + arow)*S_LEN + c*64 + acol] = pv;
        }
        // PV: out += e[:, c*64..] * V[c*64.., :]
        const int am = mg*16 + ln;
        #pragma unroll
        for (int s = 0; s < 2; ++s) {
            f16x8 af  = *(const f16x8*)&e_tile[am*S_LEN + ((c*64 + s*32 + lg*8) ^ ((am & 7) << 3))];
            f16x8 bf0 = *(const f16x8*)&kvbuf[cur][(ng*32      + ln)*72 + s*32 + lg*8];
            f16x8 bf1 = *(const f16x8*)&kvbuf[cur][(ng*32 + 16 + ln)*72 + s*32 + lg*8];
            oacc0 = __builtin_amdgcn_mfma_f32_16x16x32_f16(af, bf0, oacc0, 0, 0, 0);
            oacc1 = __builtin_amdgcn_mfma_f32_16x16x32_f16(af, bf1, oacc1, 0, 0, 0);
        }
        if (c + 1 < NCH) {
            #pragma unroll
            for (int j = 0; j < 8; ++j) {
                float x = (j < 4) ? sa[j] : sb[j-4];
                kvbuf[(c+1)&1][(st_d0 + j)*72 + st_row] = (_Float16)x;
            }
        }
        __syncthreads();
    }

    // ================= Epilogue: out = acc * inv_l =================
    #pragma unroll
    for (int tj = 0; tj < 2; ++tj) {
        const f32x4 oa = tj ? oacc1 : oacc0;
        const int n = ng*32 + tj*16 + ln;
        #pragma unroll
        for (int r = 0; r < 4; ++r) {
            const int m = mg*16 + lg*4 + r;
            outh[(size_t)(qbase + m)*DH + n] = oa[r] * inv_l[m];
        }
    }
}

extern "C" void kernel_launch(void* const* d_in, const int* in_sizes, int n_in,
                              void* d_out, int out_size, void* d_ws, size_t ws_size,
                              hipStream_t stream) {
    const float* q = (const float*)d_in[0];
    const float* k = (const float*)d_in[1];
    const float* v = (const float*)d_in[2];
    float* out = (float*)d_out;
    attn_fused<<<dim3(64 * 16), dim3(BLOCK), 0, stream>>>(q, k, v, out);
}